// Round 8
// baseline (186.443 us; speedup 1.0000x reference)
//
#include <hip/hip_runtime.h>

// Detail_loss: loss = 0.25/(98*258*256) * sum_{n,h,w} ( |D[h][w+1]-D[h][w-1]| + |D[h+1][w]-D[h-1][w]| )
// where D[n,h,w] = sum_c (infer - ref)[n,c,h,w], zero outside [0,256)^2.
// (identical per-channel-pair conv kernels -> channel-sum first; conv linearity ->
// difference first; pad rows/cols contribute 0; scale folds the 0.5 coeff, the 3
// output channels, and the /(98*3*258*256) means.)
//
// R7: 7 structures (LDS tile / wave-row / rolling window / packed waves /
// register batch / async DMA / XCD swizzle) all land at 54-63us. Time tracks
// logical-bytes / ~3.3-3.9 TB/s service regardless of structure -> queue-bound
// memory service (L3-heavy; inputs restore-warm). Only remaining lever: fewer
// requested bytes. R2's structure had the best service rate (3.9 TB/s at amp
// 1.5); this is R2 with TH=4 -> 16: halo amp 18/16 = 1.125, logical 169 MB.
// 1568 single-wave blocks = 6.1/CU (plenty of queue pressure when queue-bound).

#define W 256
#define NIMG 98
#define CH_STRIDE 65536        // 256*256
#define TH 16
#define NSTRIP 16              // 256 / TH
#define NWAVE (NIMG * NSTRIP)  // 1568 strips == blocks (1 wave each)
#define SCALE (0.25f / 6472704.0f)   // 0.25/(98*258*256)

__device__ __forceinline__ float4 load_D_row(const float* __restrict__ xb,
                                             const float* __restrict__ yb, int r) {
  float4 d = make_float4(0.f, 0.f, 0.f, 0.f);
  if (r >= 0 && r < 256) {              // wave-uniform
    const int off = r * W;
    #pragma unroll
    for (int c = 0; c < 3; ++c) {
      float4 xv = *(const float4*)(xb + c * CH_STRIDE + off);
      float4 yv = *(const float4*)(yb + c * CH_STRIDE + off);
      d.x += xv.x - yv.x;
      d.y += xv.y - yv.y;
      d.z += xv.z - yv.z;
      d.w += xv.w - yv.w;
    }
  }
  return d;
}

__global__ __launch_bounds__(64) void detail_stage1(
    const float* __restrict__ x, const float* __restrict__ y,
    float* __restrict__ partial) {
  const int lane  = threadIdx.x;        // one wave per block
  const int b     = blockIdx.x;
  const int n     = b >> 4;             // image
  const int strip = b & 15;
  const int r0    = strip * TH;

  const float* xb = x + (size_t)n * 3 * CH_STRIDE + (lane << 2);
  const float* yb = y + (size_t)n * 3 * CH_STRIDE + (lane << 2);

  float4 Dm = load_D_row(xb, yb, r0 - 1);
  float4 D0 = load_D_row(xb, yb, r0);
  float acc = 0.f;

  #pragma unroll
  for (int i = 0; i < TH; ++i) {
    float4 Dp = load_D_row(xb, yb, r0 + i + 1);   // issues while row i computes
    float left  = __shfl_up(D0.w, 1, 64);         // col 4j-1 from lane-1
    float right = __shfl_down(D0.x, 1, 64);       // col 4j+4 from lane+1
    if (lane == 0)  left  = 0.f;                  // image col -1 zero pad
    if (lane == 63) right = 0.f;                  // image col 256 zero pad
    acc += fabsf(D0.y - left)  + fabsf(D0.z - D0.x)
         + fabsf(D0.w - D0.y)  + fabsf(right - D0.z)
         + fabsf(Dp.x - Dm.x)  + fabsf(Dp.y - Dm.y)
         + fabsf(Dp.z - Dm.z)  + fabsf(Dp.w - Dm.w);
    Dm = D0; D0 = Dp;
  }

  #pragma unroll
  for (int off = 32; off > 0; off >>= 1)
    acc += __shfl_down(acc, off, 64);
  if (lane == 0) partial[b] = acc;                // per-wave slot, no contention
}

__global__ __launch_bounds__(256) void detail_stage2(
    const float* __restrict__ partial, float* __restrict__ out) {
  float acc = 0.f;
  for (int i = threadIdx.x; i < NWAVE; i += 256) acc += partial[i];
  #pragma unroll
  for (int off = 32; off > 0; off >>= 1)
    acc += __shfl_down(acc, off, 64);
  __shared__ float ws[4];
  if ((threadIdx.x & 63) == 0) ws[threadIdx.x >> 6] = acc;
  __syncthreads();
  if (threadIdx.x == 0) out[0] = (ws[0] + ws[1] + ws[2] + ws[3]) * SCALE;
}

// Fallback single-kernel variant (atomic) in case ws_size is too small.
__global__ __launch_bounds__(64) void detail_stage1_atomic(
    const float* __restrict__ x, const float* __restrict__ y,
    float* __restrict__ out) {
  const int lane  = threadIdx.x;
  const int b     = blockIdx.x;
  const int n     = b >> 4;
  const int strip = b & 15;
  const int r0    = strip * TH;
  const float* xb = x + (size_t)n * 3 * CH_STRIDE + (lane << 2);
  const float* yb = y + (size_t)n * 3 * CH_STRIDE + (lane << 2);
  float4 Dm = load_D_row(xb, yb, r0 - 1);
  float4 D0 = load_D_row(xb, yb, r0);
  float acc = 0.f;
  #pragma unroll
  for (int i = 0; i < TH; ++i) {
    float4 Dp = load_D_row(xb, yb, r0 + i + 1);
    float left  = __shfl_up(D0.w, 1, 64);
    float right = __shfl_down(D0.x, 1, 64);
    if (lane == 0)  left  = 0.f;
    if (lane == 63) right = 0.f;
    acc += fabsf(D0.y - left)  + fabsf(D0.z - D0.x)
         + fabsf(D0.w - D0.y)  + fabsf(right - D0.z)
         + fabsf(Dp.x - Dm.x)  + fabsf(Dp.y - Dm.y)
         + fabsf(Dp.z - Dm.z)  + fabsf(Dp.w - Dm.w);
    Dm = D0; D0 = Dp;
  }
  #pragma unroll
  for (int off = 32; off > 0; off >>= 1)
    acc += __shfl_down(acc, off, 64);
  if (lane == 0) atomicAdd(out, acc * SCALE);
}

extern "C" void kernel_launch(void* const* d_in, const int* in_sizes, int n_in,
                              void* d_out, int out_size, void* d_ws, size_t ws_size,
                              hipStream_t stream) {
  const float* infer = (const float*)d_in[0];
  const float* ref   = (const float*)d_in[1];
  float* out = (float*)d_out;

  if (ws_size >= NWAVE * sizeof(float)) {
    float* partial = (float*)d_ws;
    detail_stage1<<<NWAVE, 64, 0, stream>>>(infer, ref, partial);
    detail_stage2<<<1, 256, 0, stream>>>(partial, out);
  } else {
    hipMemsetAsync(out, 0, sizeof(float), stream);
    detail_stage1_atomic<<<NWAVE, 64, 0, stream>>>(infer, ref, out);
  }
}